// Round 7
// baseline (2919.795 us; speedup 1.0000x reference)
//
#include <hip/hip_runtime.h>
#include <stdint.h>
#include <math.h>

#define NIN    784
#define H1     100
#define H2     10
#define BATCH  4096
#define KC     28        // K-chunk cols; 784 = 28*28
#define NCH    28
#define KCP    32        // xib row stride (floats)
#define RT     16        // rows per block
#define NSTEP  99        // layer2 t=0..98; layer1 t=0..97

typedef float v2f __attribute__((ext_vector_type(2)));

// ---- Threefry-2x32 (jax partitionable path, verified R4/R5) ----
__device__ __forceinline__ void threefry2x32(uint32_t k0, uint32_t k1,
                                             uint32_t x0, uint32_t x1,
                                             uint32_t& o0, uint32_t& o1) {
    uint32_t ks2 = k0 ^ k1 ^ 0x1BD11BDAu;
    x0 += k0; x1 += k1;
#define TFR(r) { x0 += x1; x1 = (x1 << (r)) | (x1 >> (32 - (r))); x1 ^= x0; }
    TFR(13) TFR(15) TFR(26) TFR(6)  x0 += k1;  x1 += ks2 + 1u;
    TFR(17) TFR(29) TFR(16) TFR(24) x0 += ks2; x1 += k0 + 2u;
    TFR(13) TFR(15) TFR(26) TFR(6)  x0 += k0;  x1 += k1 + 3u;
    TFR(17) TFR(29) TFR(16) TFR(24) x0 += k1;  x1 += ks2 + 4u;
    TFR(13) TFR(15) TFR(26) TFR(6)  x0 += ks2; x1 += k0 + 5u;
#undef TFR
    o0 = x0; o1 = x1;
}

__device__ __forceinline__ float u01(uint32_t b) {
    return __uint_as_float((b >> 9) | 0x3f800000u) - 1.0f;
}

__global__ void transpose_w1(const float* __restrict__ W1, float* __restrict__ w1t) {
    int idx = blockIdx.x * 256 + threadIdx.x;
    if (idx < NIN * H1) {
        int h = idx / NIN, jj = idx - h * NIN;
        w1t[idx] = W1[jj * H1 + h];
    }
}

// GEMM over quads [Q0,Q1): 4 rows x (h0,h1), packed-f32 FMA.
template<int Q0, int Q1>
__device__ __forceinline__ void gemm_quads(const float* __restrict__ wb,
                                           const float* __restrict__ xb,
                                           int h0off, int h1off,
                                           v2f* __restrict__ acc0, v2f* __restrict__ acc1) {
#pragma unroll
    for (int jq = Q0; jq < Q1; ++jq) {
        float4 w0  = *(const float4*)&wb[h0off + jq * 4];
        float4 w1q = *(const float4*)&wb[h1off + jq * 4];
        v2f w0a = {w0.x, w0.y},   w0b = {w0.z, w0.w};
        v2f w1a = {w1q.x, w1q.y}, w1b = {w1q.z, w1q.w};
#pragma unroll
        for (int r = 0; r < 4; ++r) {
            float4 xq = *(const float4*)&xb[r * KCP + jq * 4];
            v2f xa = {xq.x, xq.y}, xb2 = {xq.z, xq.w};
            acc0[r] = __builtin_elementwise_fma(xa,  w0a, acc0[r]);
            acc0[r] = __builtin_elementwise_fma(xb2, w0b, acc0[r]);
            acc1[r] = __builtin_elementwise_fma(xa,  w1a, acc1[r]);
            acc1[r] = __builtin_elementwise_fma(xb2, w1b, acc1[r]);
        }
    }
}

__global__ __launch_bounds__(1024)
void spiking_net_kernel(const float* __restrict__ x,
                        const float* __restrict__ w1t,
                        const float* __restrict__ b1,
                        const float* __restrict__ W2,
                        const float* __restrict__ b2,
                        float* __restrict__ out) {
    __shared__ __align__(16) float    wt[2][KC * H1];    // 22400 B
    __shared__ __align__(16) float    xib[2][RT * KCP];  //  4096 B
    __shared__ __align__(16) float    o1s[RT * H1];      //  6400 B
    __shared__ __align__(16) float    w2t[H2 * H1];      //  4000 B
    __shared__ __align__(16) float    red[3 * RT * 128]; // 24576 B
    __shared__ __align__(16) float    sums[RT * H2];     //   640 B
    __shared__           uint32_t keys[200];             //   800 B  (62912 B)

    const int tid  = threadIdx.x;
    const int wv   = tid >> 6;
    const int lane = tid & 63;
    const int row0 = blockIdx.x * RT;
    const int q    = wv & 3;          // K-quarter
    const int rg   = wv >> 2;         // row-group (4 rows)

    if (tid < 100) {
        uint32_t y0, y1;
        threefry2x32(0u, 42u, 0u, (uint32_t)tid, y0, y1);
        keys[2 * tid] = y0; keys[2 * tid + 1] = y1;
    }
    for (int i = tid; i < H2 * H1; i += 1024) {
        int cc = i / H1, k = i - cc * H1;
        w2t[i] = W2[k * H2 + cc];
    }
    for (int i = tid; i < RT * H1; i += 1024) o1s[i] = 0.0f;

    // lane -> layer1 neurons h0=lane, h1=lane+64
    const int  h0    = lane;
    const bool h1v   = (lane < H1 - 64);
    const int  h1    = h1v ? (64 + lane) : (H1 - 1);
    const int  h0off = h0 * KC;
    const int  h1off = h1 * KC;
    const float b1_0 = b1[h0];
    const float b1_1 = b1[h1];
    float i1[4][2] = {{0,0},{0,0},{0,0},{0,0}};   // state on q==0 waves

    // hoisted W1-staging indices: 700 quads, threads 0..699 (chunk-invariant)
    const bool s_act = (tid < (KC * H1) / 4);
    int s_lds = 0, s_src = 0;
    if (s_act) {
        int sh = tid / 7, sj = tid - sh * 7;
        s_lds = sh * KC + sj * 4;
        s_src = sh * NIN + sj * 4;
    }

    // layer2: thread (r2, c2) for tid < 160
    const int  r2    = tid / 10;
    const int  c2    = tid - r2 * 10;
    const bool l2act = (tid < RT * H2);
    const float b2r  = l2act ? b2[c2] : 0.0f;
    float i2 = 0.0f, sum2 = 0.0f;

    __syncthreads();

    auto stage = [&](int c, int b) {
        if (s_act)
            *(float4*)&wt[b][s_lds] = *(const float4*)&w1t[s_src + c * KC];
    };
    // hash: 7 full waves per chunk, rotated across chunks for SIMD balance
    auto genxi = [&](int c, int b, uint32_t k0, uint32_t k1) {
        int slot = (wv + c) & 15;
        if (slot < 7) {
            int e  = slot * 64 + lane;            // 0..447
            int r  = e / KC, jj = e - r * KC;
            uint32_t ctr = (uint32_t)((row0 + r) * NIN + c * KC + jj);
            uint32_t y0, y1;
            threefry2x32(k0, k1, 0u, ctr, y0, y1);
            xib[b][r * KCP + jj] = u01(y0 ^ y1) * x[ctr];
        }
    };

    v2f acc0[4], acc1[4];

    for (int t = 0; t < NSTEP; ++t) {
        const uint32_t k0 = keys[2 * t], k1 = keys[2 * t + 1];
        const bool dol1 = (t < 98);

        // ---- phase A: stage+hash chunk0; layer2 on prev o1s ----
        if (dol1) {
            stage(0, 0);
            genxi(0, 0, k0, k1);
#pragma unroll
            for (int r = 0; r < 4; ++r) { acc0[r] = (v2f){0.f, 0.f}; acc1[r] = (v2f){0.f, 0.f}; }
        }
        if (l2act) {
            const float* orow = &o1s[r2 * H1];
            const float* wrow = &w2t[c2 * H1];
            float a = 0.0f;
#pragma unroll
            for (int k = 0; k < H1; k += 4) {
                float4 ov = *(const float4*)&orow[k];
                float4 wq = *(const float4*)&wrow[k];
                a = fmaf(ov.x, wq.x, a); a = fmaf(ov.y, wq.y, a);
                a = fmaf(ov.z, wq.z, a); a = fmaf(ov.w, wq.w, a);
            }
            float inner2 = (a + b2r) + i2 * 0.9f;
            float outer2 = fmaxf(inner2 - 1.0f, 0.0f);
            inner2 = (outer2 > 0.0f) ? (inner2 - 1.5f * inner2) : inner2;
            i2 = inner2;
            if (t >= 19) sum2 += inner2;
        }
        __syncthreads();

        if (dol1) {
            for (int c = 0; c < NCH; ++c) {
                const int b = c & 1;
                if (c + 1 < NCH) { stage(c + 1, b ^ 1); genxi(c + 1, b ^ 1, k0, k1); }
                const float* wb = wt[b];
                const float* xb = &xib[b][rg * (4 * KCP)];
                switch (q) {
                    case 0: gemm_quads<0, 2>(wb, xb, h0off, h1off, acc0, acc1); break;
                    case 1: gemm_quads<2, 4>(wb, xb, h0off, h1off, acc0, acc1); break;
                    case 2: gemm_quads<4, 6>(wb, xb, h0off, h1off, acc0, acc1); break;
                    default: gemm_quads<6, 7>(wb, xb, h0off, h1off, acc0, acc1); break;
                }
                __syncthreads();
            }
            // ---- publish partials (quarters 1-3) ----
            if (q > 0) {
#pragma unroll
                for (int r = 0; r < 4; ++r) {
                    red[(q - 1) * (RT * 128) + (4 * rg + r) * 128 + lane]      = acc0[r].x + acc0[r].y;
                    red[(q - 1) * (RT * 128) + (4 * rg + r) * 128 + 64 + lane] = acc1[r].x + acc1[r].y;
                }
            }
            __syncthreads();
            // ---- reduce + neuron update (q==0 waves own state) ----
            if (q == 0) {
#pragma unroll
                for (int r = 0; r < 4; ++r) {
                    float a0 = acc0[r].x + acc0[r].y;
                    float a1 = acc1[r].x + acc1[r].y;
#pragma unroll
                    for (int p = 0; p < 3; ++p) {
                        a0 += red[p * (RT * 128) + (4 * rg + r) * 128 + lane];
                        a1 += red[p * (RT * 128) + (4 * rg + r) * 128 + 64 + lane];
                    }
                    float in0  = (a0 + b1_0) + i1[r][0] * 0.9f;
                    float out0 = fmaxf(in0 - 1.0f, 0.0f);
                    in0 = (out0 > 0.0f) ? (in0 - 1.5f * in0) : in0;
                    i1[r][0] = in0;
                    o1s[(4 * rg + r) * H1 + h0] = out0;

                    float in1  = (a1 + b1_1) + i1[r][1] * 0.9f;
                    float out1 = fmaxf(in1 - 1.0f, 0.0f);
                    in1 = (out1 > 0.0f) ? (in1 - 1.5f * in1) : in1;
                    i1[r][1] = in1;
                    if (h1v) o1s[(4 * rg + r) * H1 + h1] = out1;
                }
            }
        }
        __syncthreads();
    }

    // ---- epilogue: log_softmax ----
    if (l2act) sums[r2 * H2 + c2] = sum2;
    __syncthreads();
    if (l2act) {
        float m = -INFINITY;
#pragma unroll
        for (int cc = 0; cc < H2; ++cc) m = fmaxf(m, sums[r2 * H2 + cc]);
        float s = 0.0f;
#pragma unroll
        for (int cc = 0; cc < H2; ++cc) s += expf(sums[r2 * H2 + cc] - m);
        out[(row0 + r2) * H2 + c2] = sum2 - m - logf(s);
    }
}

extern "C" void kernel_launch(void* const* d_in, const int* in_sizes, int n_in,
                              void* d_out, int out_size, void* d_ws, size_t ws_size,
                              hipStream_t stream) {
    const float* x  = (const float*)d_in[0];
    const float* W1 = (const float*)d_in[1];
    const float* b1 = (const float*)d_in[2];
    const float* W2 = (const float*)d_in[3];
    const float* b2 = (const float*)d_in[4];
    float* out = (float*)d_out;
    float* w1t = (float*)d_ws;                      // 313.6 KB scratch

    hipLaunchKernelGGL(transpose_w1, dim3((NIN * H1 + 255) / 256), dim3(256), 0, stream,
                       W1, w1t);
    // 256 blocks x 1024 threads; homogeneous waves: all stage+hash+GEMM
    // (R6's producer/consumer split caused LDS bank collisions between roles)
    hipLaunchKernelGGL(spiking_net_kernel, dim3(BATCH / RT), dim3(1024), 0, stream,
                       x, w1t, b1, W2, b2, out);
}

// Round 8
// 2129.810 us; speedup vs baseline: 1.3709x; 1.3709x over previous
//
#include <hip/hip_runtime.h>
#include <stdint.h>
#include <math.h>

#define NIN    784
#define H1     100
#define H2     10
#define BATCH  4096
#define KC     112       // K-chunk cols; 784 = 7*112
#define NCH    7
#define WTS    116       // wt row stride (dwords): 116 mod 32 = 20 -> b128 conflict-free
#define KCP    112       // xib row stride
#define RT     16        // rows per block
#define NSTEP  99        // layer2 t=0..98; layer1 t=0..97

// ---- Threefry-2x32 (jax partitionable path, verified R4+) ----
__device__ __forceinline__ void threefry2x32(uint32_t k0, uint32_t k1,
                                             uint32_t x0, uint32_t x1,
                                             uint32_t& o0, uint32_t& o1) {
    uint32_t ks2 = k0 ^ k1 ^ 0x1BD11BDAu;
    x0 += k0; x1 += k1;
#define TFR(r) { x0 += x1; x1 = (x1 << (r)) | (x1 >> (32 - (r))); x1 ^= x0; }
    TFR(13) TFR(15) TFR(26) TFR(6)  x0 += k1;  x1 += ks2 + 1u;
    TFR(17) TFR(29) TFR(16) TFR(24) x0 += ks2; x1 += k0 + 2u;
    TFR(13) TFR(15) TFR(26) TFR(6)  x0 += k0;  x1 += k1 + 3u;
    TFR(17) TFR(29) TFR(16) TFR(24) x0 += k1;  x1 += ks2 + 4u;
    TFR(13) TFR(15) TFR(26) TFR(6)  x0 += ks2; x1 += k0 + 5u;
#undef TFR
    o0 = x0; o1 = x1;
}

__device__ __forceinline__ float u01(uint32_t b) {
    return __uint_as_float((b >> 9) | 0x3f800000u) - 1.0f;
}

__global__ void transpose_w1(const float* __restrict__ W1, float* __restrict__ w1t) {
    int idx = blockIdx.x * 256 + threadIdx.x;
    if (idx < NIN * H1) {
        int h = idx / NIN, jj = idx - h * NIN;
        w1t[idx] = W1[jj * H1 + h];
    }
}

// dynamic-LDS layout (dwords):
//  wt   : 2 * 11600   (=23200)  W1 chunks, row stride WTS=116
//  xib  : 2 * 1792    (=3584)   gated inputs, row stride 112
//  o1s  : 1600                  prev-step outer1
//  w2t  : 1000                  W2 transposed
//  red  : 6144                  quarter partials
//  sums : 160
//  keys : 200 (uint32)
#define L_WT    0
#define L_XIB   23200
#define L_O1S   (L_XIB + 3584)
#define L_W2T   (L_O1S + 1600)
#define L_RED   (L_W2T + 1000)
#define L_SUMS  (L_RED + 6144)
#define L_KEYS  (L_SUMS + 160)
#define L_TOTAL (L_KEYS + 200)      // 35888 dwords = 143552 B

__global__ __launch_bounds__(1024)
void spiking_net_kernel(const float* __restrict__ x,
                        const float* __restrict__ w1t,
                        const float* __restrict__ b1,
                        const float* __restrict__ W2,
                        const float* __restrict__ b2,
                        float* __restrict__ out) {
    extern __shared__ __align__(16) float smem[];
    float*    const wt   = smem + L_WT;     // [2][100*116]
    float*    const xib  = smem + L_XIB;    // [2][16*112]
    float*    const o1s  = smem + L_O1S;    // [16*100]
    float*    const w2t  = smem + L_W2T;    // [10*100]
    float*    const red  = smem + L_RED;    // [3][16*128]
    float*    const sums = smem + L_SUMS;   // [16*10]
    uint32_t* const keys = (uint32_t*)(smem + L_KEYS);

    const int tid  = threadIdx.x;
    const int wv   = tid >> 6;
    const int lane = tid & 63;
    const int row0 = blockIdx.x * RT;
    const int g    = wv & 3;          // row-group: rows 4g..4g+3 (= SIMD id)
    const int q    = wv >> 2;         // K-quarter (7 quads each)

    if (tid < 100) {
        uint32_t y0, y1;
        threefry2x32(0u, 42u, 0u, (uint32_t)tid, y0, y1);
        keys[2 * tid] = y0; keys[2 * tid + 1] = y1;
    }
    for (int i = tid; i < H2 * H1; i += 1024) {
        int cc = i / H1, k = i - cc * H1;
        w2t[i] = W2[k * H2 + cc];
    }
    for (int i = tid; i < RT * H1; i += 1024) o1s[i] = 0.0f;

    // lane -> layer1 neurons h0=lane, h1=lane+64
    const int  h0    = lane;
    const bool h1v   = (lane < H1 - 64);
    const int  h1    = h1v ? (64 + lane) : (H1 - 1);
    const int  h0off = h0 * WTS;
    const int  h1off = h1 * WTS;
    const float b1_0 = b1[h0];
    const float b1_1 = b1[h1];
    float i1[4][2] = {{0,0},{0,0},{0,0},{0,0}};   // state on q==0 waves

    // ---- hoisted staging indices: 2800 quads/chunk, 3 per thread ----
    int  s_lds[3], s_src[3];
    bool s_v[3];
#pragma unroll
    for (int k = 0; k < 3; ++k) {
        int idx = tid + 1024 * k;
        s_v[k] = (idx < (KC * H1) / 4);           // < 2800
        int sh = idx / (KC / 4), sj = idx - sh * (KC / 4);   // /28
        s_lds[k] = sh * WTS + sj * 4;
        s_src[k] = sh * NIN + sj * 4;
    }
    // ---- hoisted hash indices: 1792 elems/chunk, 2 per thread ----
    int  hx[2], hl[2];
    bool h_v[2];
#pragma unroll
    for (int k = 0; k < 2; ++k) {
        int e = tid + 1024 * k;
        h_v[k] = (e < RT * KC);                   // < 1792
        int r = e / KC, jj = e - r * KC;
        hx[k] = (row0 + r) * NIN + jj;            // + c*KC per chunk
        hl[k] = r * KCP + jj;
    }

    // layer2: thread (r2, c2) for tid < 160
    const int  r2    = tid / 10;
    const int  c2    = tid - r2 * 10;
    const bool l2act = (tid < RT * H2);
    const float b2r  = l2act ? b2[c2] : 0.0f;
    float i2 = 0.0f, sum2 = 0.0f;

    __syncthreads();

    auto stage = [&](int c, int b) {
        float* dst = wt + b * (H1 * WTS);
        const float* src = w1t + c * KC;
#pragma unroll
        for (int k = 0; k < 3; ++k)
            if (s_v[k]) *(float4*)&dst[s_lds[k]] = *(const float4*)&src[s_src[k]];
    };
    auto genxi = [&](int c, int b, uint32_t k0, uint32_t k1) {
        float* dst = xib + b * (RT * KCP);
#pragma unroll
        for (int k = 0; k < 2; ++k) {
            if (h_v[k]) {
                uint32_t ctr = (uint32_t)(hx[k] + c * KC);
                uint32_t y0, y1;
                threefry2x32(k0, k1, 0u, ctr, y0, y1);
                dst[hl[k]] = u01(y0 ^ y1) * x[hx[k] + c * KC];
            }
        }
    };

    float acc[4][2];
    const int jqb = 7 * q;            // runtime bounds -> rolled loop (R5 codegen)
    const int jqe = 7 * q + 7;

    for (int t = 0; t < NSTEP; ++t) {
        const uint32_t k0 = keys[2 * t], k1 = keys[2 * t + 1];
        const bool dol1 = (t < 98);

        // ---- phase A: stage+hash chunk0; layer2 on prev o1s ----
        if (dol1) {
            stage(0, 0);
            genxi(0, 0, k0, k1);
#pragma unroll
            for (int r = 0; r < 4; ++r) { acc[r][0] = 0.f; acc[r][1] = 0.f; }
        }
        if (l2act) {
            const float* orow = &o1s[r2 * H1];
            const float* wrow = &w2t[c2 * H1];
            float a = 0.0f;
#pragma unroll
            for (int k = 0; k < H1; k += 4) {
                float4 ov = *(const float4*)&orow[k];
                float4 wq = *(const float4*)&wrow[k];
                a = fmaf(ov.x, wq.x, a); a = fmaf(ov.y, wq.y, a);
                a = fmaf(ov.z, wq.z, a); a = fmaf(ov.w, wq.w, a);
            }
            float inner2 = (a + b2r) + i2 * 0.9f;
            float outer2 = fmaxf(inner2 - 1.0f, 0.0f);
            inner2 = (outer2 > 0.0f) ? (inner2 - 1.5f * inner2) : inner2;
            i2 = inner2;
            if (t >= 19) sum2 += inner2;
        }
        __syncthreads();

        if (dol1) {
            for (int c = 0; c < NCH; ++c) {
                const int b = c & 1;
                if (c + 1 < NCH) { stage(c + 1, b ^ 1); genxi(c + 1, b ^ 1, k0, k1); }
                const float* wb  = wt + b * (H1 * WTS);
                const float* xr0 = xib + b * (RT * KCP) + (4 * g + 0) * KCP;
                const float* xr1 = xr0 + KCP;
                const float* xr2 = xr1 + KCP;
                const float* xr3 = xr2 + KCP;
                for (int jq = jqb; jq < jqe; ++jq) {
                    float4 w0  = *(const float4*)&wb[h0off + jq * 4];
                    float4 w1q = *(const float4*)&wb[h1off + jq * 4];
                    float4 a0 = *(const float4*)&xr0[jq * 4];
                    float4 a1 = *(const float4*)&xr1[jq * 4];
                    float4 a2 = *(const float4*)&xr2[jq * 4];
                    float4 a3 = *(const float4*)&xr3[jq * 4];
                    acc[0][0] = fmaf(a0.x, w0.x, acc[0][0]); acc[0][0] = fmaf(a0.y, w0.y, acc[0][0]);
                    acc[0][0] = fmaf(a0.z, w0.z, acc[0][0]); acc[0][0] = fmaf(a0.w, w0.w, acc[0][0]);
                    acc[0][1] = fmaf(a0.x, w1q.x, acc[0][1]); acc[0][1] = fmaf(a0.y, w1q.y, acc[0][1]);
                    acc[0][1] = fmaf(a0.z, w1q.z, acc[0][1]); acc[0][1] = fmaf(a0.w, w1q.w, acc[0][1]);
                    acc[1][0] = fmaf(a1.x, w0.x, acc[1][0]); acc[1][0] = fmaf(a1.y, w0.y, acc[1][0]);
                    acc[1][0] = fmaf(a1.z, w0.z, acc[1][0]); acc[1][0] = fmaf(a1.w, w0.w, acc[1][0]);
                    acc[1][1] = fmaf(a1.x, w1q.x, acc[1][1]); acc[1][1] = fmaf(a1.y, w1q.y, acc[1][1]);
                    acc[1][1] = fmaf(a1.z, w1q.z, acc[1][1]); acc[1][1] = fmaf(a1.w, w1q.w, acc[1][1]);
                    acc[2][0] = fmaf(a2.x, w0.x, acc[2][0]); acc[2][0] = fmaf(a2.y, w0.y, acc[2][0]);
                    acc[2][0] = fmaf(a2.z, w0.z, acc[2][0]); acc[2][0] = fmaf(a2.w, w0.w, acc[2][0]);
                    acc[2][1] = fmaf(a2.x, w1q.x, acc[2][1]); acc[2][1] = fmaf(a2.y, w1q.y, acc[2][1]);
                    acc[2][1] = fmaf(a2.z, w1q.z, acc[2][1]); acc[2][1] = fmaf(a2.w, w1q.w, acc[2][1]);
                    acc[3][0] = fmaf(a3.x, w0.x, acc[3][0]); acc[3][0] = fmaf(a3.y, w0.y, acc[3][0]);
                    acc[3][0] = fmaf(a3.z, w0.z, acc[3][0]); acc[3][0] = fmaf(a3.w, w0.w, acc[3][0]);
                    acc[3][1] = fmaf(a3.x, w1q.x, acc[3][1]); acc[3][1] = fmaf(a3.y, w1q.y, acc[3][1]);
                    acc[3][1] = fmaf(a3.z, w1q.z, acc[3][1]); acc[3][1] = fmaf(a3.w, w1q.w, acc[3][1]);
                }
                __syncthreads();
            }
            // ---- publish partials (quarters 1-3) ----
            if (q > 0) {
#pragma unroll
                for (int r = 0; r < 4; ++r) {
                    red[(q - 1) * (RT * 128) + (4 * g + r) * 128 + lane]      = acc[r][0];
                    red[(q - 1) * (RT * 128) + (4 * g + r) * 128 + 64 + lane] = acc[r][1];
                }
            }
            __syncthreads();
            // ---- reduce + neuron update (q==0 waves own state) ----
            if (q == 0) {
#pragma unroll
                for (int r = 0; r < 4; ++r) {
                    float a0 = acc[r][0], a1 = acc[r][1];
#pragma unroll
                    for (int p = 0; p < 3; ++p) {
                        a0 += red[p * (RT * 128) + (4 * g + r) * 128 + lane];
                        a1 += red[p * (RT * 128) + (4 * g + r) * 128 + 64 + lane];
                    }
                    float in0  = (a0 + b1_0) + i1[r][0] * 0.9f;
                    float out0 = fmaxf(in0 - 1.0f, 0.0f);
                    in0 = (out0 > 0.0f) ? (in0 - 1.5f * in0) : in0;
                    i1[r][0] = in0;
                    o1s[(4 * g + r) * H1 + h0] = out0;

                    float in1  = (a1 + b1_1) + i1[r][1] * 0.9f;
                    float out1 = fmaxf(in1 - 1.0f, 0.0f);
                    in1 = (out1 > 0.0f) ? (in1 - 1.5f * in1) : in1;
                    i1[r][1] = in1;
                    if (h1v) o1s[(4 * g + r) * H1 + h1] = out1;
                }
            }
        }
        __syncthreads();
    }

    // ---- epilogue: log_softmax ----
    if (l2act) sums[r2 * H2 + c2] = sum2;
    __syncthreads();
    if (l2act) {
        float m = -INFINITY;
#pragma unroll
        for (int cc = 0; cc < H2; ++cc) m = fmaxf(m, sums[r2 * H2 + cc]);
        float s = 0.0f;
#pragma unroll
        for (int cc = 0; cc < H2; ++cc) s += expf(sums[r2 * H2 + cc] - m);
        out[(row0 + r2) * H2 + c2] = sum2 - m - logf(s);
    }
}

extern "C" void kernel_launch(void* const* d_in, const int* in_sizes, int n_in,
                              void* d_out, int out_size, void* d_ws, size_t ws_size,
                              hipStream_t stream) {
    const float* x  = (const float*)d_in[0];
    const float* W1 = (const float*)d_in[1];
    const float* b1 = (const float*)d_in[2];
    const float* W2 = (const float*)d_in[3];
    const float* b2 = (const float*)d_in[4];
    float* out = (float*)d_out;
    float* w1t = (float*)d_ws;                      // 313.6 KB scratch

    hipLaunchKernelGGL(transpose_w1, dim3((NIN * H1 + 255) / 256), dim3(256), 0, stream,
                       W1, w1t);

    const size_t lds_bytes = (size_t)L_TOTAL * 4;   // 143552 B dynamic LDS
    static_assert(L_TOTAL * 4 <= 160 * 1024, "LDS over 160KB");
    hipFuncSetAttribute((const void*)spiking_net_kernel,
                        hipFuncAttributeMaxDynamicSharedMemorySize, (int)lds_bytes);
    // 256 blocks x 1024 threads, 1 block/CU; 16 waves = 4 row-groups x 4 K-quarters
    hipLaunchKernelGGL(spiking_net_kernel, dim3(BATCH / RT), dim3(1024), lds_bytes, stream,
                       x, w1t, b1, W2, b2, out);
}

// Round 9
// 1219.315 us; speedup vs baseline: 2.3946x; 1.7467x over previous
//
#include <hip/hip_runtime.h>
#include <stdint.h>
#include <math.h>

#define NIN    784
#define H1     100
#define H2     10
#define BATCH  4096
#define RT     16        // rows per block
#define NSTEP  99        // layer2 t=0..98; layer1 t=0..97
#define WROWS  112       // padded N for W planes
#define WK     800       // padded K (25 tiles of 32)
#define AS     808       // A-plane row stride in halfs (404 dw == 20 mod 32 -> 2-way free)

typedef _Float16 h16;
typedef h16  h8  __attribute__((ext_vector_type(8)));
typedef h16  h2t __attribute__((ext_vector_type(2)));
typedef float f4 __attribute__((ext_vector_type(4)));

// ---- dynamic LDS layout (dwords) ----
#define L_A     0                    // 2 bufs x (hi,lo) x 16 x 404 = 25856 dw
#define L_O1S   25856                // 1600
#define L_W2T   27456                // 1000
#define L_RED   28456                // 7 x 256 = 1792
#define L_SUMS  30248                // 160
#define L_KEYS  30408                // 200
#define L_TOTAL 30608                // 122,432 B

// ---- Threefry-2x32 (jax partitionable path, verified R4+) ----
__device__ __forceinline__ void threefry2x32(uint32_t k0, uint32_t k1,
                                             uint32_t x0, uint32_t x1,
                                             uint32_t& o0, uint32_t& o1) {
    uint32_t ks2 = k0 ^ k1 ^ 0x1BD11BDAu;
    x0 += k0; x1 += k1;
#define TFR(r) { x0 += x1; x1 = (x1 << (r)) | (x1 >> (32 - (r))); x1 ^= x0; }
    TFR(13) TFR(15) TFR(26) TFR(6)  x0 += k1;  x1 += ks2 + 1u;
    TFR(17) TFR(29) TFR(16) TFR(24) x0 += ks2; x1 += k0 + 2u;
    TFR(13) TFR(15) TFR(26) TFR(6)  x0 += k0;  x1 += k1 + 3u;
    TFR(17) TFR(29) TFR(16) TFR(24) x0 += k1;  x1 += ks2 + 4u;
    TFR(13) TFR(15) TFR(26) TFR(6)  x0 += ks2; x1 += k0 + 5u;
#undef TFR
    o0 = x0; o1 = x1;
}

__device__ __forceinline__ float u01(uint32_t b) {
    return __uint_as_float((b >> 9) | 0x3f800000u) - 1.0f;
}

// W1 -> transposed hi/lo f16 planes: w1hi[h][k] = f16(W1[k][h]), w1lo = f16((w-hi)*4096)
__global__ void prep_w1(const float* __restrict__ W1, h16* __restrict__ w1hi,
                        h16* __restrict__ w1lo) {
    int idx = blockIdx.x * 256 + threadIdx.x;
    if (idx < WROWS * WK) {
        int h = idx / WK, k = idx - h * WK;
        float w = (h < H1 && k < NIN) ? W1[k * H1 + h] : 0.0f;
        h16 wh = (h16)w;
        h16 wl = (h16)((w - (float)wh) * 4096.0f);
        w1hi[idx] = wh; w1lo[idx] = wl;
    }
}

__global__ __launch_bounds__(1024)
void spiking_net_kernel(const float* __restrict__ x,
                        const h16* __restrict__ w1hi,
                        const h16* __restrict__ w1lo,
                        const float* __restrict__ b1,
                        const float* __restrict__ W2,
                        const float* __restrict__ b2,
                        float* __restrict__ out) {
    extern __shared__ __align__(16) float smem[];
    float*    const o1s  = smem + L_O1S;
    float*    const w2t  = smem + L_W2T;
    float*    const red  = smem + L_RED;
    float*    const sums = smem + L_SUMS;
    uint32_t* const keys = (uint32_t*)(smem + L_KEYS);

    const int tid  = threadIdx.x;
    const int wv   = tid >> 6;
    const int lane = tid & 63;
    const int row0 = blockIdx.x * RT;

    // MFMA roles: waves 0..13 -> (Ntile = wv>>1, K-half = wv&1); 14,15 hash-only
    const bool mfm = (wv < 14);
    const int  nt  = wv >> 1;
    const int  kh  = wv & 1;

    // ---- init ----
    if (tid < 100) {
        uint32_t y0, y1;
        threefry2x32(0u, 42u, 0u, (uint32_t)tid, y0, y1);
        keys[2 * tid] = y0; keys[2 * tid + 1] = y1;
    }
    for (int i = tid; i < H2 * H1; i += 1024) {
        int cc = i / H1, k = i - cc * H1;
        w2t[i] = W2[k * H2 + cc];
    }
    for (int i = tid; i < RT * H1; i += 1024) o1s[i] = 0.0f;
    for (int i = tid; i < L_O1S; i += 1024) smem[i] = 0.0f;   // zero A planes (K-pad!)

    // MFMA per-lane constants
    const int  aoff = (lane & 15) * AS + (lane >> 4) * 8;     // A-frag: m=lane&15, k=8*quad+j
    const int  n    = (nt << 4) + (lane & 15);                // output neuron
    const int  boff = n * WK + (lane >> 4) * 8;               // B-frag: n=lane&15, k=8*quad+j
    const bool nv   = (n < H1);
    const float b1v = (mfm && kh == 0) ? b1[nv ? n : 0] : 0.0f;
    float i1[4] = {0.f, 0.f, 0.f, 0.f};                       // state on kh==0 waves

    // hash: wave w owns row w; 784 = 7*112 pairs
    const int      hrow = wv;
    const uint32_t rb   = (uint32_t)((row0 + hrow) * NIN);
    const float*   xr   = x + (row0 + hrow) * NIN;

    // layer2: thread (r2,c2) for tid<160
    const int  r2    = tid / 10;
    const int  c2    = tid - r2 * 10;
    const bool l2act = (tid < RT * H2);
    const float b2r  = l2act ? b2[c2] : 0.0f;
    float i2 = 0.0f, sum2 = 0.0f;

    __syncthreads();

    auto hashrow = [&](int buf, uint32_t hk0, uint32_t hk1) {
        h16* ah = (h16*)(smem + buf * 12928)        + hrow * AS;
        h16* al = (h16*)(smem + buf * 12928 + 6464) + hrow * AS;
#pragma unroll
        for (int it = 0; it < 7; ++it) {
            int kd = (it << 6) + lane;              // dword index: covers k=2kd,2kd+1
            if (it < 6 || lane < 8) {
                uint32_t c0 = rb + (uint32_t)(2 * kd);
                uint32_t a0, a1, q0, q1;
                threefry2x32(hk0, hk1, 0u, c0,      a0, a1);
                threefry2x32(hk0, hk1, 0u, c0 + 1u, q0, q1);
                float2 xv = *(const float2*)(xr + 2 * kd);
                float v0 = u01(a0 ^ a1) * xv.x;
                float v1 = u01(q0 ^ q1) * xv.y;
                h16 hh0 = (h16)v0, hh1 = (h16)v1;
                h16 ll0 = (h16)((v0 - (float)hh0) * 4096.0f);
                h16 ll1 = (h16)((v1 - (float)hh1) * 4096.0f);
                h2t ph; ph.x = hh0; ph.y = hh1;
                h2t pl; pl.x = ll0; pl.y = ll1;
                *(h2t*)(ah + 2 * kd) = ph;
                *(h2t*)(al + 2 * kd) = pl;
            }
        }
    };

    // prologue: xi(0) -> buf 0
    hashrow(0, keys[0], keys[1]);
    __syncthreads();

    f4 cc;

    for (int t = 0; t < NSTEP; ++t) {
        const bool dog = (t < 98);

        // ================= phase 1 =================
        if (dog && mfm) {
            const h16* Ah = (const h16*)(smem + (t & 1) * 12928);
            const h16* Al = (const h16*)(smem + (t & 1) * 12928 + 6464);
            f4 accM = {0.f, 0.f, 0.f, 0.f};
            f4 accS = {0.f, 0.f, 0.f, 0.f};
            if (kh == 0) {
#pragma unroll
                for (int kt = 0; kt < 13; ++kt) {
                    h8 avh = *(const h8*)(Ah + aoff + kt * 32);
                    h8 avl = *(const h8*)(Al + aoff + kt * 32);
                    h8 bvh = *(const h8*)(w1hi + boff + kt * 32);
                    h8 bvl = *(const h8*)(w1lo + boff + kt * 32);
                    accM = __builtin_amdgcn_mfma_f32_16x16x32_f16(avh, bvh, accM, 0, 0, 0);
                    accS = __builtin_amdgcn_mfma_f32_16x16x32_f16(avl, bvh, accS, 0, 0, 0);
                    accS = __builtin_amdgcn_mfma_f32_16x16x32_f16(avh, bvl, accS, 0, 0, 0);
                }
            } else {
#pragma unroll
                for (int kt = 13; kt < 25; ++kt) {
                    h8 avh = *(const h8*)(Ah + aoff + kt * 32);
                    h8 avl = *(const h8*)(Al + aoff + kt * 32);
                    h8 bvh = *(const h8*)(w1hi + boff + kt * 32);
                    h8 bvl = *(const h8*)(w1lo + boff + kt * 32);
                    accM = __builtin_amdgcn_mfma_f32_16x16x32_f16(avh, bvh, accM, 0, 0, 0);
                    accS = __builtin_amdgcn_mfma_f32_16x16x32_f16(avl, bvh, accS, 0, 0, 0);
                    accS = __builtin_amdgcn_mfma_f32_16x16x32_f16(avh, bvl, accS, 0, 0, 0);
                }
            }
            cc = accM + accS * 0.000244140625f;    // + accS/4096 (lo planes pre-scaled)
            if (kh == 1) *(f4*)(red + nt * 256 + lane * 4) = cc;
        }
        if (t < 97) hashrow((t + 1) & 1, keys[2 * (t + 1)], keys[2 * (t + 1) + 1]);
        if (l2act) {
            const float* orow = &o1s[r2 * H1];
            const float* wrow = &w2t[c2 * H1];
            float a = 0.0f;
#pragma unroll
            for (int k = 0; k < H1; k += 4) {
                float4 ov = *(const float4*)&orow[k];
                float4 wq = *(const float4*)&wrow[k];
                a = fmaf(ov.x, wq.x, a); a = fmaf(ov.y, wq.y, a);
                a = fmaf(ov.z, wq.z, a); a = fmaf(ov.w, wq.w, a);
            }
            float inner2 = (a + b2r) + i2 * 0.9f;
            float outer2 = fmaxf(inner2 - 1.0f, 0.0f);
            inner2 = (outer2 > 0.0f) ? (inner2 - 1.5f * inner2) : inner2;
            i2 = inner2;
            if (t >= 19) sum2 += inner2;
        }
        __syncthreads();

        // ================= phase 2: reduce + neuron update =================
        if (dog && mfm && kh == 0) {
            f4 other = *(const f4*)(red + nt * 256 + lane * 4);
#pragma unroll
            for (int rg = 0; rg < 4; ++rg) {
                float a  = (cc[rg] + other[rg]) + b1v;
                float in = a + i1[rg] * 0.9f;
                float o  = fmaxf(in - 1.0f, 0.0f);
                in = (o > 0.0f) ? (in - 1.5f * in) : in;
                i1[rg] = in;
                if (nv) o1s[((lane >> 4) * 4 + rg) * H1 + n] = o;   // C/D: row=quad*4+reg
            }
        }
        __syncthreads();
    }

    // ---- epilogue: log_softmax ----
    if (l2act) sums[r2 * H2 + c2] = sum2;
    __syncthreads();
    if (l2act) {
        float m = -INFINITY;
#pragma unroll
        for (int cc2 = 0; cc2 < H2; ++cc2) m = fmaxf(m, sums[r2 * H2 + cc2]);
        float s = 0.0f;
#pragma unroll
        for (int cc2 = 0; cc2 < H2; ++cc2) s += expf(sums[r2 * H2 + cc2] - m);
        out[(row0 + r2) * H2 + c2] = sum2 - m - logf(s);
    }
}

extern "C" void kernel_launch(void* const* d_in, const int* in_sizes, int n_in,
                              void* d_out, int out_size, void* d_ws, size_t ws_size,
                              hipStream_t stream) {
    const float* x  = (const float*)d_in[0];
    const float* W1 = (const float*)d_in[1];
    const float* b1 = (const float*)d_in[2];
    const float* W2 = (const float*)d_in[3];
    const float* b2 = (const float*)d_in[4];
    float* out = (float*)d_out;
    h16* w1hi = (h16*)d_ws;                          // 112*800 halfs = 179,200 B
    h16* w1lo = w1hi + WROWS * WK;                   // total ws use: 358,400 B

    hipLaunchKernelGGL(prep_w1, dim3((WROWS * WK + 255) / 256), dim3(256), 0, stream,
                       W1, w1hi, w1lo);

    const size_t lds_bytes = (size_t)L_TOTAL * 4;    // 122,432 B
    hipFuncSetAttribute((const void*)spiking_net_kernel,
                        hipFuncAttributeMaxDynamicSharedMemorySize, (int)lds_bytes);
    hipLaunchKernelGGL(spiking_net_kernel, dim3(BATCH / RT), dim3(1024), lds_bytes, stream,
                       x, w1hi, w1lo, b1, W2, b2, out);
}

// Round 10
// 1215.038 us; speedup vs baseline: 2.4030x; 1.0035x over previous
//
#include <hip/hip_runtime.h>
#include <stdint.h>
#include <math.h>

#define NIN    784
#define H1     100
#define H2     10
#define BATCH  4096
#define RT     16        // rows per block
#define WROWS  112       // padded N for W planes
#define WK     800       // padded K (25 tiles of 32)
#define AS     808       // A-plane row stride in halfs (404 dw == 20 mod 32)

typedef _Float16 h16;
typedef h16  h8  __attribute__((ext_vector_type(8)));
typedef h16  h2t __attribute__((ext_vector_type(2)));
typedef float f4 __attribute__((ext_vector_type(4)));

// ---- dynamic LDS layout (dwords) ----
#define L_A     0                    // 2 bufs x (hi,lo) x 16 x 404 = 25856
#define L_O1S   25856                // 2 x 1600 = 3200 (double-buffered outer1)
#define L_W2T   29056                // 1000
#define L_RED   30056                // 2 x 7 x 256 = 3584 (double-buffered partials)
#define L_SUMS  33640                // 160
#define L_KEYS  33800                // 200
#define L_TOTAL 34000                // 136,000 B

// ---- Threefry-2x32 (jax partitionable path, verified R4+) ----
__device__ __forceinline__ void threefry2x32(uint32_t k0, uint32_t k1,
                                             uint32_t x0, uint32_t x1,
                                             uint32_t& o0, uint32_t& o1) {
    uint32_t ks2 = k0 ^ k1 ^ 0x1BD11BDAu;
    x0 += k0; x1 += k1;
#define TFR(r) { x0 += x1; x1 = __builtin_rotateleft32(x1, r); x1 ^= x0; }
    TFR(13) TFR(15) TFR(26) TFR(6)  x0 += k1;  x1 += ks2 + 1u;
    TFR(17) TFR(29) TFR(16) TFR(24) x0 += ks2; x1 += k0 + 2u;
    TFR(13) TFR(15) TFR(26) TFR(6)  x0 += k0;  x1 += k1 + 3u;
    TFR(17) TFR(29) TFR(16) TFR(24) x0 += k1;  x1 += ks2 + 4u;
    TFR(13) TFR(15) TFR(26) TFR(6)  x0 += ks2; x1 += k0 + 5u;
#undef TFR
    o0 = x0; o1 = x1;
}

__device__ __forceinline__ float u01(uint32_t b) {
    return __uint_as_float((b >> 9) | 0x3f800000u) - 1.0f;
}

// W1 -> transposed hi/lo f16 planes (lo pre-scaled x4096 to dodge f16 denorms)
__global__ void prep_w1(const float* __restrict__ W1, h16* __restrict__ w1hi,
                        h16* __restrict__ w1lo) {
    int idx = blockIdx.x * 256 + threadIdx.x;
    if (idx < WROWS * WK) {
        int h = idx / WK, k = idx - h * WK;
        float w = (h < H1 && k < NIN) ? W1[k * H1 + h] : 0.0f;
        h16 wh = (h16)w;
        h16 wl = (h16)((w - (float)wh) * 4096.0f);
        w1hi[idx] = wh; w1lo[idx] = wl;
    }
}

__global__ __launch_bounds__(1024)
void spiking_net_kernel(const float* __restrict__ x,
                        const h16* __restrict__ w1hi,
                        const h16* __restrict__ w1lo,
                        const float* __restrict__ b1,
                        const float* __restrict__ W2,
                        const float* __restrict__ b2,
                        float* __restrict__ out) {
    extern __shared__ __align__(16) float smem[];
    float*    const o1s  = smem + L_O1S;    // [2][16*100]
    float*    const w2t  = smem + L_W2T;
    float*    const red  = smem + L_RED;    // [2][7*256]
    float*    const sums = smem + L_SUMS;
    uint32_t* const keys = (uint32_t*)(smem + L_KEYS);

    const int tid  = threadIdx.x;
    const int wv   = tid >> 6;
    const int lane = tid & 63;
    const int row0 = blockIdx.x * RT;

    // MFMA roles: waves 0..13 -> (Ntile = wv>>1, K-half = wv&1); 14,15 hash-only
    const bool mfm = (wv < 14);
    const int  nt  = wv >> 1;
    const int  kh  = wv & 1;

    // ---- init ----
    if (tid < 100) {
        uint32_t y0, y1;
        threefry2x32(0u, 42u, 0u, (uint32_t)tid, y0, y1);
        keys[2 * tid] = y0; keys[2 * tid + 1] = y1;
    }
    for (int i = tid; i < H2 * H1; i += 1024) {
        int cc2 = i / H1, k = i - cc2 * H1;
        w2t[i] = W2[k * H2 + cc2];
    }
    for (int i = tid; i < 2 * RT * H1; i += 1024) o1s[i] = 0.0f;   // both buffers
    for (int i = tid; i < L_O1S; i += 1024) smem[i] = 0.0f;        // A planes (K-pad)

    // MFMA per-lane constants
    const int  aoff = (lane & 15) * AS + (lane >> 4) * 8;     // A: m=lane&15, k=8*quad+j
    const int  n    = (nt << 4) + (lane & 15);                // output neuron
    const int  boff = n * WK + (lane >> 4) * 8;               // B: n=lane&15, k=8*quad+j
    const bool nv   = (n < H1);
    const float b1v = (mfm && kh == 0) ? b1[nv ? n : 0] : 0.0f;
    float i1[4] = {0.f, 0.f, 0.f, 0.f};                       // state on kh==0 waves

    // hash: wave w owns row w
    const int      hrow = wv;
    const uint32_t rb   = (uint32_t)((row0 + hrow) * NIN);
    const float*   xr   = x + (row0 + hrow) * NIN;

    // layer2: thread (r2,c2) for tid<160
    const int  r2    = tid / 10;
    const int  c2    = tid - r2 * 10;
    const bool l2act = (tid < RT * H2);
    const float b2r  = l2act ? b2[c2] : 0.0f;
    float i2 = 0.0f, sum2 = 0.0f;

    __syncthreads();

    auto hashrow = [&](int buf, uint32_t hk0, uint32_t hk1) {
        h16* ah = (h16*)(smem + buf * 12928)        + hrow * AS;
        h16* al = (h16*)(smem + buf * 12928 + 6464) + hrow * AS;
#pragma unroll
        for (int it = 0; it < 7; ++it) {
            int kd = (it << 6) + lane;              // dword idx: elements 2kd, 2kd+1
            if (it < 6 || lane < 8) {
                uint32_t c0 = rb + (uint32_t)(2 * kd);
                uint32_t a0, a1, q0, q1;
                threefry2x32(hk0, hk1, 0u, c0,      a0, a1);
                threefry2x32(hk0, hk1, 0u, c0 + 1u, q0, q1);
                float2 xv = *(const float2*)(xr + 2 * kd);
                float v0 = u01(a0 ^ a1) * xv.x;
                float v1 = u01(q0 ^ q1) * xv.y;
                h16 hh0 = (h16)v0, hh1 = (h16)v1;   // bit-identical to R9 path
                h16 ll0 = (h16)((v0 - (float)hh0) * 4096.0f);
                h16 ll1 = (h16)((v1 - (float)hh1) * 4096.0f);
                h2t ph; ph.x = hh0; ph.y = hh1;
                h2t pl; pl.x = ll0; pl.y = ll1;
                *(h2t*)(ah + 2 * kd) = ph;
                *(h2t*)(al + 2 * kd) = pl;
            }
        }
    };

    // prologue: xi(0) -> buf 0
    hashrow(0, keys[0], keys[1]);
    __syncthreads();

    f4 cc;   // MFMA result of step t, consumed (update) in phase t+1

    // ---- software-pipelined main loop: ONE barrier per phase ----
    // phase t: update(t-1) | MFMA(t) | hash(t+1) | layer2(t-1)
    for (int t = 0; t < 100; ++t) {
        // 1) neuron update for step t-1 (kh==0 waves own state)
        if (t >= 1 && t < 99 && mfm && kh == 0) {
            const float* rp = red + ((t - 1) & 1) * 1792 + nt * 256 + lane * 4;
            f4 other = *(const f4*)rp;
            float* op = o1s + ((t - 1) & 1) * 1600;
#pragma unroll
            for (int rg = 0; rg < 4; ++rg) {
                float a  = (cc[rg] + other[rg]) + b1v;
                float in = a + i1[rg] * 0.9f;
                float o  = fmaxf(in - 1.0f, 0.0f);
                in = (o > 0.0f) ? (in - 1.5f * in) : in;
                i1[rg] = in;
                if (nv) op[((lane >> 4) * 4 + rg) * H1 + n] = o;   // C/D row=quad*4+reg
            }
        }
        // 2) MFMA for step t
        if (t < 98 && mfm) {
            const h16* Ah = (const h16*)(smem + (t & 1) * 12928);
            const h16* Al = (const h16*)(smem + (t & 1) * 12928 + 6464);
            f4 accM = {0.f, 0.f, 0.f, 0.f};
            f4 accS = {0.f, 0.f, 0.f, 0.f};
            if (kh == 0) {
#pragma unroll
                for (int kt = 0; kt < 13; ++kt) {
                    h8 avh = *(const h8*)(Ah + aoff + kt * 32);
                    h8 avl = *(const h8*)(Al + aoff + kt * 32);
                    h8 bvh = *(const h8*)(w1hi + boff + kt * 32);
                    h8 bvl = *(const h8*)(w1lo + boff + kt * 32);
                    accM = __builtin_amdgcn_mfma_f32_16x16x32_f16(avh, bvh, accM, 0, 0, 0);
                    accS = __builtin_amdgcn_mfma_f32_16x16x32_f16(avl, bvh, accS, 0, 0, 0);
                    accS = __builtin_amdgcn_mfma_f32_16x16x32_f16(avh, bvl, accS, 0, 0, 0);
                }
            } else {
#pragma unroll
                for (int kt = 13; kt < 25; ++kt) {
                    h8 avh = *(const h8*)(Ah + aoff + kt * 32);
                    h8 avl = *(const h8*)(Al + aoff + kt * 32);
                    h8 bvh = *(const h8*)(w1hi + boff + kt * 32);
                    h8 bvl = *(const h8*)(w1lo + boff + kt * 32);
                    accM = __builtin_amdgcn_mfma_f32_16x16x32_f16(avh, bvh, accM, 0, 0, 0);
                    accS = __builtin_amdgcn_mfma_f32_16x16x32_f16(avl, bvh, accS, 0, 0, 0);
                    accS = __builtin_amdgcn_mfma_f32_16x16x32_f16(avh, bvl, accS, 0, 0, 0);
                }
            }
            cc = accM + accS * 0.000244140625f;    // + accS/4096
            if (kh == 1) *(f4*)(red + (t & 1) * 1792 + nt * 256 + lane * 4) = cc;
        }
        // 3) hash xi for step t+1
        if (t < 97) hashrow((t + 1) & 1, keys[2 * (t + 1)], keys[2 * (t + 1) + 1]);
        // 4) layer2 for step t-1 (reads outer1(t-2) = o1s[t&1])
        if (t >= 1 && l2act) {
            const float* orow = o1s + (t & 1) * 1600 + r2 * H1;
            const float* wrow = &w2t[c2 * H1];
            float a = 0.0f;
#pragma unroll
            for (int k = 0; k < H1; k += 4) {
                float4 ov = *(const float4*)&orow[k];
                float4 wq = *(const float4*)&wrow[k];
                a = fmaf(ov.x, wq.x, a); a = fmaf(ov.y, wq.y, a);
                a = fmaf(ov.z, wq.z, a); a = fmaf(ov.w, wq.w, a);
            }
            float inner2 = (a + b2r) + i2 * 0.9f;
            float outer2 = fmaxf(inner2 - 1.0f, 0.0f);
            inner2 = (outer2 > 0.0f) ? (inner2 - 1.5f * inner2) : inner2;
            i2 = inner2;
            if (t >= 20) sum2 += inner2;           // step s=t-1 >= 19
        }
        __syncthreads();
    }

    // ---- epilogue: log_softmax ----
    if (l2act) sums[r2 * H2 + c2] = sum2;
    __syncthreads();
    if (l2act) {
        float m = -INFINITY;
#pragma unroll
        for (int cc2 = 0; cc2 < H2; ++cc2) m = fmaxf(m, sums[r2 * H2 + cc2]);
        float s = 0.0f;
#pragma unroll
        for (int cc2 = 0; cc2 < H2; ++cc2) s += expf(sums[r2 * H2 + cc2] - m);
        out[(row0 + r2) * H2 + c2] = sum2 - m - logf(s);
    }
}

extern "C" void kernel_launch(void* const* d_in, const int* in_sizes, int n_in,
                              void* d_out, int out_size, void* d_ws, size_t ws_size,
                              hipStream_t stream) {
    const float* x  = (const float*)d_in[0];
    const float* W1 = (const float*)d_in[1];
    const float* b1 = (const float*)d_in[2];
    const float* W2 = (const float*)d_in[3];
    const float* b2 = (const float*)d_in[4];
    float* out = (float*)d_out;
    h16* w1hi = (h16*)d_ws;                          // 179,200 B
    h16* w1lo = w1hi + WROWS * WK;                   // ws total 358,400 B

    hipLaunchKernelGGL(prep_w1, dim3((WROWS * WK + 255) / 256), dim3(256), 0, stream,
                       W1, w1hi, w1lo);

    const size_t lds_bytes = (size_t)L_TOTAL * 4;    // 136,000 B
    hipFuncSetAttribute((const void*)spiking_net_kernel,
                        hipFuncAttributeMaxDynamicSharedMemorySize, (int)lds_bytes);
    hipLaunchKernelGGL(spiking_net_kernel, dim3(BATCH / RT), dim3(1024), lds_bytes, stream,
                       x, w1hi, w1lo, b1, W2, b2, out);
}